// Round 3
// baseline (468.956 us; speedup 1.0000x reference)
//
#include <hip/hip_runtime.h>

#define DECAY_F 0.99f
#define OMD_F   0.01f
#define EPS_F   1e-5f

typedef __attribute__((ext_vector_type(8))) __bf16 bf16x8;
typedef __attribute__((ext_vector_type(4))) float  f32x4;

// ---------------- ws layout (byte offsets) ----------------
#define WSB_CNTI     0          // 1024 i32 (4096 B)   [memset]
#define WSB_LOSS     4096       // 256 f32  (1024 B)   [memset]
#define WSB_MEMSET   5120       // memset range [0, 5120)
#define WSB_CSUM     5120       // 1 f32
#define WSB_ENORM    5632       // 1024 f32 (4096 B)
#define WSB_IDX      9728       // 32768 i32 (131072 B)
#define WSB_EHI      140800     // 262144 ushort (524288 B)
#define WSB_ELO      665088     // 262144 ushort (524288 B)
#define WSB_OFFS     1189376    // 1025 i32 (4104 B)
#define WSB_CURSOR   1193480    // 1024 i32 (4096 B)
#define WSB_SORTED   1197576    // 32768 i32 (131072 B)

// ---------------- out layout (float offsets) ----------------
#define OUT_ZQ    0
#define OUT_LOSS  8388608
#define OUT_IDX   8388609
#define OUT_EMB   8421377
#define OUT_CS    8683521
#define OUT_EMAW  8684545

// ---------- bf16 split helpers (RNE, no NaN inputs) ----------
__device__ __forceinline__ unsigned short f2bf(float x) {
    unsigned u = __builtin_bit_cast(unsigned, x);
    u += 0x7fffu + ((u >> 16) & 1u);
    return (unsigned short)(u >> 16);
}
__device__ __forceinline__ float bf2f(unsigned short h) {
    return __builtin_bit_cast(float, (unsigned)h << 16);
}
__device__ __forceinline__ void split8(const float4 a, const float4 b,
                                       uint4& hi, uint4& lo) {
    float f[8] = {a.x, a.y, a.z, a.w, b.x, b.y, b.z, b.w};
    unsigned short h[8], l[8];
    #pragma unroll
    for (int i = 0; i < 8; ++i) {
        h[i] = f2bf(f[i]);
        l[i] = f2bf(f[i] - bf2f(h[i]));
    }
    hi.x = (unsigned)h[0] | ((unsigned)h[1] << 16);
    hi.y = (unsigned)h[2] | ((unsigned)h[3] << 16);
    hi.z = (unsigned)h[4] | ((unsigned)h[5] << 16);
    hi.w = (unsigned)h[6] | ((unsigned)h[7] << 16);
    lo.x = (unsigned)l[0] | ((unsigned)l[1] << 16);
    lo.y = (unsigned)l[2] | ((unsigned)l[3] << 16);
    lo.z = (unsigned)l[4] | ((unsigned)l[5] << 16);
    lo.w = (unsigned)l[6] | ((unsigned)l[7] << 16);
}

// ============ kernel 0: split embedding to bf16 hi/lo + ||e||^2 (fused) ============
__global__ __launch_bounds__(256)
void esplit_enorm_kernel(const float* __restrict__ emb,
                         unsigned short* __restrict__ e_hi,
                         unsigned short* __restrict__ e_lo,
                         float* __restrict__ enorm) {
    const int tid = threadIdx.x, lane = tid & 63, wv = tid >> 6;
    const int k = blockIdx.x * 4 + wv;
    const float4 v = *(const float4*)(emb + (size_t)k * 256 + lane * 4);
    float f[4] = {v.x, v.y, v.z, v.w};
    unsigned short h[4], l[4];
    #pragma unroll
    for (int i = 0; i < 4; ++i) { h[i] = f2bf(f[i]); l[i] = f2bf(f[i] - bf2f(h[i])); }
    uint2 hi, lo;
    hi.x = (unsigned)h[0] | ((unsigned)h[1] << 16);
    hi.y = (unsigned)h[2] | ((unsigned)h[3] << 16);
    lo.x = (unsigned)l[0] | ((unsigned)l[1] << 16);
    lo.y = (unsigned)l[2] | ((unsigned)l[3] << 16);
    *(uint2*)(e_hi + (size_t)k * 256 + lane * 4) = hi;
    *(uint2*)(e_lo + (size_t)k * 256 + lane * 4) = lo;
    float s = v.x * v.x + v.y * v.y + v.z * v.z + v.w * v.w;
    #pragma unroll
    for (int off = 32; off > 0; off >>= 1) s += __shfl_down(s, off);
    if (lane == 0) enorm[k] = s;
}

// ============ kernel 1: MFMA argmin (3-term bf16 split GEMM) ============
// Block 256 thr = 4 waves (2 row-halves x 2 col-halves). Block tile: 128 rows x 256
// codes (ct loop = 4 over K_CODES). Wave tile 64x128 = 4x8 grid of 16x16x32 MFMAs.
// BK=32. Combos (AhBh, AhBl, AlBh) share one fp32 acc; AlBl (~2^-18) dropped.
// LDS 48 KB single-buffered; register prefetch pipeline hides global latency.
// launch_bounds(256,1): 1 block/CU, ~300 VGPR budget OK (cap 512 at 1 wave/SIMD).
__global__ __launch_bounds__(256, 1)
void argmin_kernel(const float* __restrict__ z,
                   const unsigned short* __restrict__ e_hi,
                   const unsigned short* __restrict__ e_lo,
                   const float* __restrict__ enorm,
                   int* __restrict__ idx_out, float* __restrict__ idxf_out,
                   int* __restrict__ counts_i) {
    __shared__ unsigned short Ah[128 * 32], Al[128 * 32];   // 8 KB each
    __shared__ unsigned short Bh[256 * 32], Bl[256 * 32];   // 16 KB each

    const int tid  = threadIdx.x;
    const int lane = tid & 63;
    const int wv   = tid >> 6;
    const int wy   = wv >> 1, wx = wv & 1;
    const int tx   = lane & 15, quad = lane >> 4;
    const int row0 = blockIdx.x * 128;

    // ---- staging maps ----
    const int rA0 = tid >> 2,         gA0 = tid & 3;
    const int rA1 = (tid + 256) >> 2, gA1 = (tid + 256) & 3;
    const float* zA0 = z + (size_t)(row0 + rA0) * 256 + gA0 * 8;
    const float* zA1 = z + (size_t)(row0 + rA1) * 256 + gA1 * 8;
    const int offA0 = rA0 * 32 + ((gA0 ^ (rA0 & 3)) << 3);
    const int offA1 = rA1 * 32 + ((gA1 ^ (rA1 & 3)) << 3);
    int cB[4], gB[4], offB[4];
    #pragma unroll
    for (int t = 0; t < 4; ++t) {
        const int s = tid + t * 256;
        cB[t] = s >> 2; gB[t] = s & 3;
        offB[t] = cB[t] * 32 + ((gB[t] ^ (cB[t] & 3)) << 3);
    }

    // ---- frag read offsets ----
    int offAf[4], offBf[8];
    #pragma unroll
    for (int i = 0; i < 4; ++i) {
        const int rt = wy * 64 + i * 16 + tx;
        offAf[i] = rt * 32 + ((quad ^ (rt & 3)) << 3);
    }
    #pragma unroll
    for (int j = 0; j < 8; ++j) {
        const int cb = wx * 128 + j * 16 + tx;
        offBf[j] = cb * 32 + ((quad ^ (cb & 3)) << 3);
    }

    float bestd[4][4];
    int   besti[4][4];
    #pragma unroll
    for (int i = 0; i < 4; ++i)
        #pragma unroll
        for (int r = 0; r < 4; ++r) { bestd[i][r] = 3.4e38f; besti[i][r] = 0; }

    // prefetch registers
    float4 pA[4]; uint4 pBh[4], pBl[4];
    auto prefetch = [&](int ct_, int kc_) {
        pA[0] = *(const float4*)(zA0 + kc_ * 32);
        pA[1] = *(const float4*)(zA0 + kc_ * 32 + 4);
        pA[2] = *(const float4*)(zA1 + kc_ * 32);
        pA[3] = *(const float4*)(zA1 + kc_ * 32 + 4);
        #pragma unroll
        for (int t = 0; t < 4; ++t) {
            const size_t gb = (size_t)(ct_ * 256 + cB[t]) * 256 + kc_ * 32 + gB[t] * 8;
            pBh[t] = *(const uint4*)(e_hi + gb);
            pBl[t] = *(const uint4*)(e_lo + gb);
        }
    };

    prefetch(0, 0);

    for (int ct = 0; ct < 4; ++ct) {
        f32x4 acc[4][8];
        #pragma unroll
        for (int i = 0; i < 4; ++i)
            #pragma unroll
            for (int j = 0; j < 8; ++j) acc[i][j] = (f32x4)0.0f;

        for (int kc = 0; kc < 8; ++kc) {
            __syncthreads();
            {   // regs -> LDS (split A on the fly)
                uint4 h0, l0, h1, l1;
                split8(pA[0], pA[1], h0, l0);
                split8(pA[2], pA[3], h1, l1);
                *(uint4*)(Ah + offA0) = h0; *(uint4*)(Al + offA0) = l0;
                *(uint4*)(Ah + offA1) = h1; *(uint4*)(Al + offA1) = l1;
                #pragma unroll
                for (int t = 0; t < 4; ++t) {
                    *(uint4*)(Bh + offB[t]) = pBh[t];
                    *(uint4*)(Bl + offB[t]) = pBl[t];
                }
            }
            __syncthreads();
            // issue next prefetch; vmcnt-wait lands at next iteration's LDS write,
            // hidden behind this iteration's 96 MFMAs
            if (kc < 7)      prefetch(ct, kc + 1);
            else if (ct < 3) prefetch(ct + 1, 0);

            bf16x8 ah[4], al[4], bh[8], bl[8];
            #pragma unroll
            for (int i = 0; i < 4; ++i) {
                ah[i] = __builtin_bit_cast(bf16x8, *(const uint4*)(Ah + offAf[i]));
                al[i] = __builtin_bit_cast(bf16x8, *(const uint4*)(Al + offAf[i]));
            }
            #pragma unroll
            for (int j = 0; j < 8; ++j) {
                bh[j] = __builtin_bit_cast(bf16x8, *(const uint4*)(Bh + offBf[j]));
                bl[j] = __builtin_bit_cast(bf16x8, *(const uint4*)(Bl + offBf[j]));
            }
            #pragma unroll
            for (int j = 0; j < 8; ++j)
                #pragma unroll
                for (int i = 0; i < 4; ++i)
                    acc[i][j] = __builtin_amdgcn_mfma_f32_16x16x32_bf16(ah[i], bh[j], acc[i][j], 0, 0, 0);
            #pragma unroll
            for (int j = 0; j < 8; ++j)
                #pragma unroll
                for (int i = 0; i < 4; ++i)
                    acc[i][j] = __builtin_amdgcn_mfma_f32_16x16x32_bf16(ah[i], bl[j], acc[i][j], 0, 0, 0);
            #pragma unroll
            for (int j = 0; j < 8; ++j)
                #pragma unroll
                for (int i = 0; i < 4; ++i)
                    acc[i][j] = __builtin_amdgcn_mfma_f32_16x16x32_bf16(al[i], bh[j], acc[i][j], 0, 0, 0);
        }

        // ---- distances + running argmin (codes ascend with ct: first-occurrence kept) ----
        #pragma unroll
        for (int j = 0; j < 8; ++j) {
            const int col = ct * 256 + wx * 128 + j * 16 + tx;
            const float en = enorm[col];
            #pragma unroll
            for (int i = 0; i < 4; ++i)
                #pragma unroll
                for (int r = 0; r < 4; ++r) {
                    const float d = fmaf(-2.0f, acc[i][j][r], en);
                    if (d < bestd[i][r] || (d == bestd[i][r] && col < besti[i][r])) {
                        bestd[i][r] = d; besti[i][r] = col;
                    }
                }
        }
    }

    // ---- butterfly reduce over the 16 tx lanes ----
    #pragma unroll
    for (int m = 1; m < 16; m <<= 1) {
        #pragma unroll
        for (int i = 0; i < 4; ++i)
            #pragma unroll
            for (int r = 0; r < 4; ++r) {
                const float od = __shfl_xor(bestd[i][r], m);
                const int   oi = __shfl_xor(besti[i][r], m);
                if (od < bestd[i][r] || (od == bestd[i][r] && oi < besti[i][r])) {
                    bestd[i][r] = od; besti[i][r] = oi;
                }
            }
    }

    // ---- merge wx halves via LDS (reuse Ah after barrier) ----
    __syncthreads();
    float* mg_d = (float*)Ah;                 // [2][128]
    int*   mg_i = (int*)Ah + 256;             // [2][128]
    if (tx == 0) {
        #pragma unroll
        for (int i = 0; i < 4; ++i)
            #pragma unroll
            for (int r = 0; r < 4; ++r) {
                const int rb = wy * 64 + i * 16 + quad * 4 + r;
                mg_d[wx * 128 + rb] = bestd[i][r];
                mg_i[wx * 128 + rb] = besti[i][r];
            }
    }
    __syncthreads();
    if (tid < 128) {
        float d0 = mg_d[tid];        int i0 = mg_i[tid];
        const float d1 = mg_d[128 + tid]; const int i1 = mg_i[128 + tid];
        if (d1 < d0 || (d1 == d0 && i1 < i0)) { d0 = d1; i0 = i1; }
        idx_out[row0 + tid]  = i0;
        idxf_out[row0 + tid] = (float)i0;
        atomicAdd(&counts_i[i0], 1);
    }
}

// ============ kernel 2: out_cs + csum + prefix-scan of counts -> offsets/cursor ============
__global__ __launch_bounds__(256)
void update_cs_kernel(const float* __restrict__ ema_cs, const int* __restrict__ cnt_i,
                      float* __restrict__ out_cs, float* __restrict__ csum,
                      int* __restrict__ offsets, int* __restrict__ cursor) {
    __shared__ float redf[256];
    __shared__ int wsum[4];
    const int t = threadIdx.x, lane = t & 63, wv = t >> 6;
    const int k0 = t * 4;
    const int c0 = cnt_i[k0], c1 = cnt_i[k0 + 1], c2 = cnt_i[k0 + 2], c3 = cnt_i[k0 + 3];
    const int e1 = c0, e2 = c0 + c1, e3 = e2 + c2, ts = e3 + c3;

    const float f0 = DECAY_F * ema_cs[k0]     + OMD_F * (float)c0;
    const float f1 = DECAY_F * ema_cs[k0 + 1] + OMD_F * (float)c1;
    const float f2 = DECAY_F * ema_cs[k0 + 2] + OMD_F * (float)c2;
    const float f3 = DECAY_F * ema_cs[k0 + 3] + OMD_F * (float)c3;
    out_cs[k0] = f0; out_cs[k0 + 1] = f1; out_cs[k0 + 2] = f2; out_cs[k0 + 3] = f3;
    redf[t] = f0 + f1 + f2 + f3;

    // wave-inclusive scan of ts
    int v = ts;
    #pragma unroll
    for (int o = 1; o < 64; o <<= 1) {
        const int u = __shfl_up(v, o);
        if (lane >= o) v += u;
    }
    if (lane == 63) wsum[wv] = v;
    __syncthreads();
    int wbase = 0;
    #pragma unroll
    for (int w = 0; w < 4; ++w) if (w < wv) wbase += wsum[w];
    const int texcl = wbase + v - ts;
    offsets[k0] = texcl;          cursor[k0] = texcl;
    offsets[k0 + 1] = texcl + e1; cursor[k0 + 1] = texcl + e1;
    offsets[k0 + 2] = texcl + e2; cursor[k0 + 2] = texcl + e2;
    offsets[k0 + 3] = texcl + e3; cursor[k0 + 3] = texcl + e3;
    if (t == 255) offsets[1024] = 32768;

    __syncthreads();
    #pragma unroll
    for (int off = 128; off > 0; off >>= 1) {
        if (t < off) redf[t] += redf[t + off];
        __syncthreads();
    }
    if (t == 0) csum[0] = redf[0];
}

// ============ kernel 3: scatter rows into code-sorted order ============
__global__ __launch_bounds__(256)
void scatter_kernel(const int* __restrict__ idx, int* __restrict__ cursor,
                    int* __restrict__ sorted) {
    const int n = blockIdx.x * 256 + threadIdx.x;
    const int k = idx[n];
    const int p = atomicAdd(&cursor[k], 1);
    sorted[p] = n;
}

// ============ kernel 4: gather z_q + loss partials ============
__global__ __launch_bounds__(256)
void gather_kernel(const float* __restrict__ z, const float* __restrict__ emb,
                   const int* __restrict__ idx, float* __restrict__ out_zq,
                   float* __restrict__ lossbuf) {
    const int tid  = threadIdx.x;
    const int lane = tid & 63;
    const int n    = blockIdx.x * 4 + (tid >> 6);
    const int k    = idx[n];

    const float4 e4 = *(const float4*)(emb + (size_t)k * 256 + lane * 4);
    const float4 x4 = *(const float4*)(z   + (size_t)n * 256 + lane * 4);
    *(float4*)(out_zq + (size_t)n * 256 + lane * 4) = e4;

    const float dx = e4.x - x4.x, dy = e4.y - x4.y, dz = e4.z - x4.z, dw_ = e4.w - x4.w;
    float s = dx * dx + dy * dy + dz * dz + dw_ * dw_;
    #pragma unroll
    for (int off = 32; off > 0; off >>= 1) s += __shfl_down(s, off);
    if (lane == 0) atomicAdd(&lossbuf[n & 255], s);
}

// ============ kernel 5: per-code dw (sorted segment) + EMA epilogue + loss ============
__global__ __launch_bounds__(256)
void dw_update_kernel(const float* __restrict__ z, const int* __restrict__ sorted,
                      const int* __restrict__ offsets, const float* __restrict__ lossbuf,
                      const float* __restrict__ ema_w, const float* __restrict__ out_cs,
                      const float* __restrict__ csum,
                      float* __restrict__ out_emb, float* __restrict__ out_emaw,
                      float* __restrict__ out_loss) {
    __shared__ float red[256];
    const int k = blockIdx.x;
    const int t = threadIdx.x;

    if (k == 0) {
        red[t] = lossbuf[t]; __syncthreads();
        #pragma unroll
        for (int off = 128; off > 0; off >>= 1) {
            if (t < off) red[t] += red[t + off];
            __syncthreads();
        }
        if (t == 0) out_loss[0] = 1.25f * red[0] / 8388608.0f;
    }

    const int beg = offsets[k], end = offsets[k + 1];
    float s0 = 0.0f, s1 = 0.0f, s2 = 0.0f, s3 = 0.0f;
    int j = beg;
    for (; j + 3 < end; j += 4) {
        const int r0 = sorted[j], r1 = sorted[j + 1], r2 = sorted[j + 2], r3 = sorted[j + 3];
        s0 += z[(size_t)r0 * 256 + t];
        s1 += z[(size_t)r1 * 256 + t];
        s2 += z[(size_t)r2 * 256 + t];
        s3 += z[(size_t)r3 * 256 + t];
    }
    for (; j < end; ++j) s0 += z[(size_t)sorted[j] * 256 + t];
    const float s = (s0 + s1) + (s2 + s3);

    const float n_total = csum[0];
    const float cs = (out_cs[k] + EPS_F) / (n_total + 1024.0f * EPS_F) * n_total;
    const float nw = DECAY_F * ema_w[(size_t)k * 256 + t] + OMD_F * s;
    out_emaw[(size_t)k * 256 + t] = nw;
    out_emb [(size_t)k * 256 + t] = nw / cs;
}

// ======================= launcher =======================
extern "C" void kernel_launch(void* const* d_in, const int* in_sizes, int n_in,
                              void* d_out, int out_size, void* d_ws, size_t ws_size,
                              hipStream_t stream) {
    const float* z      = (const float*)d_in[0];
    const float* emb    = (const float*)d_in[1];
    const float* ema_cs = (const float*)d_in[2];
    const float* ema_w  = (const float*)d_in[3];

    float* out = (float*)d_out;
    char*  wsb = (char*)d_ws;

    int*            cnt_i   = (int*)(wsb + WSB_CNTI);
    float*          lossbuf = (float*)(wsb + WSB_LOSS);
    float*          csum    = (float*)(wsb + WSB_CSUM);
    float*          enorm   = (float*)(wsb + WSB_ENORM);
    int*            idx     = (int*)(wsb + WSB_IDX);
    unsigned short* e_hi    = (unsigned short*)(wsb + WSB_EHI);
    unsigned short* e_lo    = (unsigned short*)(wsb + WSB_ELO);
    int*            offsets = (int*)(wsb + WSB_OFFS);
    int*            cursor  = (int*)(wsb + WSB_CURSOR);
    int*            sorted  = (int*)(wsb + WSB_SORTED);

    float* out_zq   = out + OUT_ZQ;
    float* out_loss = out + OUT_LOSS;
    float* out_idxf = out + OUT_IDX;
    float* out_emb  = out + OUT_EMB;
    float* out_cs   = out + OUT_CS;
    float* out_emaw = out + OUT_EMAW;

    hipMemsetAsync(d_ws, 0, WSB_MEMSET, stream);

    esplit_enorm_kernel<<<256, 256, 0, stream>>>(emb, e_hi, e_lo, enorm);
    argmin_kernel<<<256, 256, 0, stream>>>(z, e_hi, e_lo, enorm, idx, out_idxf, cnt_i);
    update_cs_kernel<<<1, 256, 0, stream>>>(ema_cs, cnt_i, out_cs, csum, offsets, cursor);
    scatter_kernel<<<128, 256, 0, stream>>>(idx, cursor, sorted);
    gather_kernel<<<8192, 256, 0, stream>>>(z, emb, idx, out_zq, lossbuf);
    dw_update_kernel<<<1024, 256, 0, stream>>>(z, sorted, offsets, lossbuf, ema_w,
                                               out_cs, csum, out_emb, out_emaw, out_loss);
}

// Round 4
// 317.738 us; speedup vs baseline: 1.4759x; 1.4759x over previous
//
#include <hip/hip_runtime.h>

#define DECAY_F 0.99f
#define OMD_F   0.01f
#define EPS_F   1e-5f

typedef __attribute__((ext_vector_type(8))) __bf16 bf16x8;
typedef __attribute__((ext_vector_type(4))) float  f32x4;

// ---------------- ws layout (byte offsets) ----------------
#define WSB_CNTI     0          // 1024 i32                [memset]
#define WSB_LOSS     4096       // 256 f32                 [memset]
#define WSB_CSUM     5120       // 1 f32                   [memset]
#define WSB_DWACC    8192       // 262144 f32 (1 MB)       [memset]
#define WSB_MEMSET   1056768    // memset range [0, this)
#define WSB_ENORM    1056768    // 1024 f32
#define WSB_IDX      1060864    // 32768 i32
#define WSB_EHI      1191936    // 262144 ushort
#define WSB_ELO      1716224    // 262144 ushort
#define WSB_OFFS     2240512    // 1025 i32
#define WSB_CURS     2244616    // 1024 i32
#define WSB_SORT     2248712    // 32768 i32
#define WSB_BESTD    2379784    // 4*32768 f32
#define WSB_BESTI    2904072    // 4*32768 i32  (end 3428360)

// ---------------- out layout (float offsets) ----------------
#define OUT_ZQ    0
#define OUT_LOSS  8388608
#define OUT_IDX   8388609
#define OUT_EMB   8421377
#define OUT_CS    8683521
#define OUT_EMAW  8684545

// ---------- bf16 split helpers (RNE, no NaN inputs) ----------
__device__ __forceinline__ unsigned short f2bf(float x) {
    unsigned u = __builtin_bit_cast(unsigned, x);
    u += 0x7fffu + ((u >> 16) & 1u);
    return (unsigned short)(u >> 16);
}
__device__ __forceinline__ float bf2f(unsigned short h) {
    return __builtin_bit_cast(float, (unsigned)h << 16);
}
__device__ __forceinline__ void split8(const float4 a, const float4 b,
                                       uint4& hi, uint4& lo) {
    float f[8] = {a.x, a.y, a.z, a.w, b.x, b.y, b.z, b.w};
    unsigned short h[8], l[8];
    #pragma unroll
    for (int i = 0; i < 8; ++i) {
        h[i] = f2bf(f[i]);
        l[i] = f2bf(f[i] - bf2f(h[i]));
    }
    hi.x = (unsigned)h[0] | ((unsigned)h[1] << 16);
    hi.y = (unsigned)h[2] | ((unsigned)h[3] << 16);
    hi.z = (unsigned)h[4] | ((unsigned)h[5] << 16);
    hi.w = (unsigned)h[6] | ((unsigned)h[7] << 16);
    lo.x = (unsigned)l[0] | ((unsigned)l[1] << 16);
    lo.y = (unsigned)l[2] | ((unsigned)l[3] << 16);
    lo.z = (unsigned)l[4] | ((unsigned)l[5] << 16);
    lo.w = (unsigned)l[6] | ((unsigned)l[7] << 16);
}

// ============ kernel 0: split embedding to bf16 hi/lo + ||e||^2 ============
__global__ __launch_bounds__(256)
void esplit_enorm_kernel(const float* __restrict__ emb,
                         unsigned short* __restrict__ e_hi,
                         unsigned short* __restrict__ e_lo,
                         float* __restrict__ enorm) {
    const int tid = threadIdx.x, lane = tid & 63, wv = tid >> 6;
    const int k = blockIdx.x * 4 + wv;
    const float4 v = *(const float4*)(emb + (size_t)k * 256 + lane * 4);
    float f[4] = {v.x, v.y, v.z, v.w};
    unsigned short h[4], l[4];
    #pragma unroll
    for (int i = 0; i < 4; ++i) { h[i] = f2bf(f[i]); l[i] = f2bf(f[i] - bf2f(h[i])); }
    uint2 hi, lo;
    hi.x = (unsigned)h[0] | ((unsigned)h[1] << 16);
    hi.y = (unsigned)h[2] | ((unsigned)h[3] << 16);
    lo.x = (unsigned)l[0] | ((unsigned)l[1] << 16);
    lo.y = (unsigned)l[2] | ((unsigned)l[3] << 16);
    *(uint2*)(e_hi + (size_t)k * 256 + lane * 4) = hi;
    *(uint2*)(e_lo + (size_t)k * 256 + lane * 4) = lo;
    float s = v.x * v.x + v.y * v.y + v.z * v.z + v.w * v.w;
    #pragma unroll
    for (int off = 32; off > 0; off >>= 1) s += __shfl_down(s, off);
    if (lane == 0) enorm[k] = s;
}

// ============ kernel 1: MFMA argmin, code-split blocks ============
// Grid 1024 = 256 row-groups (fast) x 4 code-splits (slow). Block: 128 rows x 256
// codes, 4 waves (2x2), wave tile 64x128 = 4x8 of 16x16x32 MFMAs, kc loop only.
// 3-combo bf16 hi/lo split GEMM (AlBl ~2^-16 dropped). LDS rows padded to 40
// halfs -> <=2-way bank aliasing (free, m136). 2 blocks/CU.
__global__ __launch_bounds__(256, 2)
void argmin_kernel(const float* __restrict__ z,
                   const unsigned short* __restrict__ e_hi,
                   const unsigned short* __restrict__ e_lo,
                   const float* __restrict__ enorm,
                   float* __restrict__ best_d, int* __restrict__ best_i) {
    __shared__ unsigned short Ah[128 * 40], Al[128 * 40];   // 10 KB each
    __shared__ unsigned short Bh[256 * 40], Bl[256 * 40];   // 20 KB each

    const int tid  = threadIdx.x;
    const int lane = tid & 63;
    const int wv   = tid >> 6;
    const int wy   = wv >> 1, wx = wv & 1;
    const int tx   = lane & 15, quad = lane >> 4;
    const int rowg = blockIdx.x & 255;
    const int csp  = blockIdx.x >> 8;
    const int row0 = rowg * 128;
    const int col0 = csp * 256;

    // ---- staging maps ----
    const int rA0 = tid >> 2,         qA0 = tid & 3;
    const int rA1 = (tid + 256) >> 2, qA1 = (tid + 256) & 3;
    const float* zA0 = z + (size_t)(row0 + rA0) * 256 + qA0 * 8;
    const float* zA1 = z + (size_t)(row0 + rA1) * 256 + qA1 * 8;
    const int offA0 = rA0 * 40 + qA0 * 8;
    const int offA1 = rA1 * 40 + qA1 * 8;
    int offB[4]; const unsigned short *pBhG[4], *pBlG[4];
    #pragma unroll
    for (int p = 0; p < 4; ++p) {
        const int s = tid + p * 256;
        const int cB = s >> 2, qB = s & 3;
        offB[p] = cB * 40 + qB * 8;
        pBhG[p] = e_hi + (size_t)(col0 + cB) * 256 + qB * 8;
        pBlG[p] = e_lo + (size_t)(col0 + cB) * 256 + qB * 8;
    }

    // ---- frag read offsets (halfs) ----
    int offAf[4], offBf[8];
    #pragma unroll
    for (int i = 0; i < 4; ++i)
        offAf[i] = (wy * 64 + i * 16 + tx) * 40 + quad * 8;
    #pragma unroll
    for (int j = 0; j < 8; ++j)
        offBf[j] = (wx * 128 + j * 16 + tx) * 40 + quad * 8;

    f32x4 acc[4][8];
    #pragma unroll
    for (int i = 0; i < 4; ++i)
        #pragma unroll
        for (int j = 0; j < 8; ++j) acc[i][j] = (f32x4)0.0f;

    // ---- prefetch regs ----
    float4 pA[4]; uint4 pBh[4], pBl[4];
    auto prefetch = [&](int kc_) {
        const int o = kc_ * 32;
        pA[0] = *(const float4*)(zA0 + o);
        pA[1] = *(const float4*)(zA0 + o + 4);
        pA[2] = *(const float4*)(zA1 + o);
        pA[3] = *(const float4*)(zA1 + o + 4);
        #pragma unroll
        for (int p = 0; p < 4; ++p) {
            pBh[p] = *(const uint4*)(pBhG[p] + o);
            pBl[p] = *(const uint4*)(pBlG[p] + o);
        }
    };
    prefetch(0);

    for (int kc = 0; kc < 8; ++kc) {
        __syncthreads();
        {
            uint4 h0, l0, h1, l1;
            split8(pA[0], pA[1], h0, l0);
            split8(pA[2], pA[3], h1, l1);
            *(uint4*)(Ah + offA0) = h0; *(uint4*)(Al + offA0) = l0;
            *(uint4*)(Ah + offA1) = h1; *(uint4*)(Al + offA1) = l1;
            #pragma unroll
            for (int p = 0; p < 4; ++p) {
                *(uint4*)(Bh + offB[p]) = pBh[p];
                *(uint4*)(Bl + offB[p]) = pBl[p];
            }
        }
        __syncthreads();
        if (kc < 7) prefetch(kc + 1);

        bf16x8 ah[4], al[4], bh[8], bl[8];
        #pragma unroll
        for (int i = 0; i < 4; ++i) {
            ah[i] = __builtin_bit_cast(bf16x8, *(const uint4*)(Ah + offAf[i]));
            al[i] = __builtin_bit_cast(bf16x8, *(const uint4*)(Al + offAf[i]));
        }
        #pragma unroll
        for (int j = 0; j < 8; ++j) {
            bh[j] = __builtin_bit_cast(bf16x8, *(const uint4*)(Bh + offBf[j]));
            bl[j] = __builtin_bit_cast(bf16x8, *(const uint4*)(Bl + offBf[j]));
        }
        #pragma unroll
        for (int j = 0; j < 8; ++j)
            #pragma unroll
            for (int i = 0; i < 4; ++i)
                acc[i][j] = __builtin_amdgcn_mfma_f32_16x16x32_bf16(ah[i], bh[j], acc[i][j], 0, 0, 0);
        #pragma unroll
        for (int j = 0; j < 8; ++j)
            #pragma unroll
            for (int i = 0; i < 4; ++i)
                acc[i][j] = __builtin_amdgcn_mfma_f32_16x16x32_bf16(ah[i], bl[j], acc[i][j], 0, 0, 0);
        #pragma unroll
        for (int j = 0; j < 8; ++j)
            #pragma unroll
            for (int i = 0; i < 4; ++i)
                acc[i][j] = __builtin_amdgcn_mfma_f32_16x16x32_bf16(al[i], bh[j], acc[i][j], 0, 0, 0);
    }

    // ---- distances + in-thread argmin over j (codes ascending) ----
    float bestd[4][4];
    int   besti[4][4];
    #pragma unroll
    for (int i = 0; i < 4; ++i)
        #pragma unroll
        for (int r = 0; r < 4; ++r) { bestd[i][r] = 3.4e38f; besti[i][r] = 0; }
    #pragma unroll
    for (int j = 0; j < 8; ++j) {
        const int col = col0 + wx * 128 + j * 16 + tx;
        const float en = enorm[col];
        #pragma unroll
        for (int i = 0; i < 4; ++i)
            #pragma unroll
            for (int r = 0; r < 4; ++r) {
                const float d = fmaf(-2.0f, acc[i][j][r], en);
                if (d < bestd[i][r] || (d == bestd[i][r] && col < besti[i][r])) {
                    bestd[i][r] = d; besti[i][r] = col;
                }
            }
    }

    // ---- butterfly over the 16 tx lanes ----
    #pragma unroll
    for (int m = 1; m < 16; m <<= 1) {
        #pragma unroll
        for (int i = 0; i < 4; ++i)
            #pragma unroll
            for (int r = 0; r < 4; ++r) {
                const float od = __shfl_xor(bestd[i][r], m);
                const int   oi = __shfl_xor(besti[i][r], m);
                if (od < bestd[i][r] || (od == bestd[i][r] && oi < besti[i][r])) {
                    bestd[i][r] = od; besti[i][r] = oi;
                }
            }
    }

    // ---- merge wx halves via LDS, write per-split best ----
    __syncthreads();
    float* mg_d = (float*)Ah;                 // [2][128]
    int*   mg_i = (int*)Ah + 256;
    if (tx == 0) {
        #pragma unroll
        for (int i = 0; i < 4; ++i)
            #pragma unroll
            for (int r = 0; r < 4; ++r) {
                const int rb = wy * 64 + i * 16 + quad * 4 + r;
                mg_d[wx * 128 + rb] = bestd[i][r];
                mg_i[wx * 128 + rb] = besti[i][r];
            }
    }
    __syncthreads();
    if (tid < 128) {
        float d0 = mg_d[tid];            int i0 = mg_i[tid];
        const float d1 = mg_d[128 + tid]; const int i1 = mg_i[128 + tid];
        if (d1 < d0 || (d1 == d0 && i1 < i0)) { d0 = d1; i0 = i1; }
        best_d[csp * 32768 + row0 + tid] = d0;
        best_i[csp * 32768 + row0 + tid] = i0;
    }
}

// ============ kernel 2: merge code-splits -> idx, counts ============
__global__ __launch_bounds__(256)
void merge_kernel(const float* __restrict__ best_d, const int* __restrict__ best_i,
                  int* __restrict__ idx, float* __restrict__ idxf,
                  int* __restrict__ cnt_i) {
    const int r = blockIdx.x * 256 + threadIdx.x;
    float d = best_d[r]; int i = best_i[r];
    #pragma unroll
    for (int s = 1; s < 4; ++s) {
        const float ds = best_d[s * 32768 + r];
        const int   is_ = best_i[s * 32768 + r];
        if (ds < d) { d = ds; i = is_; }   // higher split => higher code: strict <
    }
    idx[r] = i;
    idxf[r] = (float)i;
    atomicAdd(&cnt_i[i], 1);
}

// ============ kernel 3: out_cs + csum + prefix-scan -> offsets/cursor ============
__global__ __launch_bounds__(256)
void update_cs_kernel(const float* __restrict__ ema_cs, const int* __restrict__ cnt_i,
                      float* __restrict__ out_cs, float* __restrict__ csum,
                      int* __restrict__ offsets, int* __restrict__ cursor) {
    __shared__ float redf[256];
    __shared__ int wsum[4];
    const int t = threadIdx.x, lane = t & 63, wv = t >> 6;
    const int k0 = t * 4;
    const int c0 = cnt_i[k0], c1 = cnt_i[k0 + 1], c2 = cnt_i[k0 + 2], c3 = cnt_i[k0 + 3];
    const int e1 = c0, e2 = c0 + c1, e3 = e2 + c2, ts = e3 + c3;

    const float f0 = DECAY_F * ema_cs[k0]     + OMD_F * (float)c0;
    const float f1 = DECAY_F * ema_cs[k0 + 1] + OMD_F * (float)c1;
    const float f2 = DECAY_F * ema_cs[k0 + 2] + OMD_F * (float)c2;
    const float f3 = DECAY_F * ema_cs[k0 + 3] + OMD_F * (float)c3;
    out_cs[k0] = f0; out_cs[k0 + 1] = f1; out_cs[k0 + 2] = f2; out_cs[k0 + 3] = f3;
    redf[t] = f0 + f1 + f2 + f3;

    int v = ts;
    #pragma unroll
    for (int o = 1; o < 64; o <<= 1) {
        const int u = __shfl_up(v, o);
        if (lane >= o) v += u;
    }
    if (lane == 63) wsum[wv] = v;
    __syncthreads();
    int wbase = 0;
    #pragma unroll
    for (int w = 0; w < 4; ++w) if (w < wv) wbase += wsum[w];
    const int texcl = wbase + v - ts;
    offsets[k0] = texcl;          cursor[k0] = texcl;
    offsets[k0 + 1] = texcl + e1; cursor[k0 + 1] = texcl + e1;
    offsets[k0 + 2] = texcl + e2; cursor[k0 + 2] = texcl + e2;
    offsets[k0 + 3] = texcl + e3; cursor[k0 + 3] = texcl + e3;
    if (t == 255) offsets[1024] = 32768;

    __syncthreads();
    #pragma unroll
    for (int off = 128; off > 0; off >>= 1) {
        if (t < off) redf[t] += redf[t + off];
        __syncthreads();
    }
    if (t == 0) csum[0] = redf[0];
}

// ============ kernel 4: scatter rows into code-sorted order ============
__global__ __launch_bounds__(256)
void scatter_kernel(const int* __restrict__ idx, int* __restrict__ cursor,
                    int* __restrict__ sorted) {
    const int n = blockIdx.x * 256 + threadIdx.x;
    const int k = idx[n];
    const int p = atomicAdd(&cursor[k], 1);
    sorted[p] = n;
}

// ============ kernel 5: gather z_q + loss partials ============
__global__ __launch_bounds__(256)
void gather_kernel(const float* __restrict__ z, const float* __restrict__ emb,
                   const int* __restrict__ idx, float* __restrict__ out_zq,
                   float* __restrict__ lossbuf) {
    const int tid  = threadIdx.x;
    const int lane = tid & 63;
    const int n    = blockIdx.x * 4 + (tid >> 6);
    const int k    = idx[n];

    const float4 e4 = *(const float4*)(emb + (size_t)k * 256 + lane * 4);
    const float4 x4 = *(const float4*)(z   + (size_t)n * 256 + lane * 4);
    *(float4*)(out_zq + (size_t)n * 256 + lane * 4) = e4;

    const float dx = e4.x - x4.x, dy = e4.y - x4.y, dz = e4.z - x4.z, dw_ = e4.w - x4.w;
    float s = dx * dx + dy * dy + dz * dz + dw_ * dw_;
    #pragma unroll
    for (int off = 32; off > 0; off >>= 1) s += __shfl_down(s, off);
    if (lane == 0) atomicAdd(&lossbuf[n & 255], s);
}

// ============ kernel 6: dw scatter — fixed work units, run-length flush ============
// Wave owns 16 consecutive SORTED rows; registers accumulate a run of equal
// codes; one float4 atomicAdd per run boundary. Load-balanced regardless of skew.
__global__ __launch_bounds__(256)
void dw_scatter_kernel(const float* __restrict__ z, const int* __restrict__ sorted,
                       const int* __restrict__ idx, float* __restrict__ dwacc) {
    const int lane = threadIdx.x & 63;
    const int w    = blockIdx.x * 4 + (threadIdx.x >> 6);
    const int r0   = w * 16;

    float4 s = make_float4(0.f, 0.f, 0.f, 0.f);
    int krun = idx[sorted[r0]];
    for (int j = 0; j < 16; ++j) {
        const int row = sorted[r0 + j];
        const int k   = idx[row];
        if (k != krun) {
            float* p = dwacc + (size_t)krun * 256 + lane * 4;
            atomicAdd(p + 0, s.x); atomicAdd(p + 1, s.y);
            atomicAdd(p + 2, s.z); atomicAdd(p + 3, s.w);
            s = make_float4(0.f, 0.f, 0.f, 0.f);
            krun = k;
        }
        const float4 v = *(const float4*)(z + (size_t)row * 256 + lane * 4);
        s.x += v.x; s.y += v.y; s.z += v.z; s.w += v.w;
    }
    float* p = dwacc + (size_t)krun * 256 + lane * 4;
    atomicAdd(p + 0, s.x); atomicAdd(p + 1, s.y);
    atomicAdd(p + 2, s.z); atomicAdd(p + 3, s.w);
}

// ============ kernel 7: EMA-w / embedding epilogue + loss finalize ============
__global__ __launch_bounds__(256)
void update_w_kernel(const float* __restrict__ ema_w, const float* __restrict__ dwacc,
                     const float* __restrict__ out_cs, const float* __restrict__ csum,
                     const float* __restrict__ lossbuf,
                     float* __restrict__ out_emb, float* __restrict__ out_emaw,
                     float* __restrict__ out_loss) {
    __shared__ float red[256];
    const int t = threadIdx.x;
    if (blockIdx.x == 0) {
        red[t] = lossbuf[t]; __syncthreads();
        #pragma unroll
        for (int off = 128; off > 0; off >>= 1) {
            if (t < off) red[t] += red[t + off];
            __syncthreads();
        }
        if (t == 0) out_loss[0] = 1.25f * red[0] / 8388608.0f;
    }

    const int g = blockIdx.x * 256 + t;          // float4 slot, 0..65535
    const int k = g >> 6;
    const float n_total = csum[0];
    const float cs = (out_cs[k] + EPS_F) / (n_total + 1024.0f * EPS_F) * n_total;

    const float4 w4 = *(const float4*)(ema_w + (size_t)g * 4);
    const float4 d4 = *(const float4*)(dwacc + (size_t)g * 4);
    float4 nw, ne;
    nw.x = DECAY_F * w4.x + OMD_F * d4.x;
    nw.y = DECAY_F * w4.y + OMD_F * d4.y;
    nw.z = DECAY_F * w4.z + OMD_F * d4.z;
    nw.w = DECAY_F * w4.w + OMD_F * d4.w;
    ne.x = nw.x / cs; ne.y = nw.y / cs; ne.z = nw.z / cs; ne.w = nw.w / cs;
    *(float4*)(out_emaw + (size_t)g * 4) = nw;
    *(float4*)(out_emb  + (size_t)g * 4) = ne;
}

// ======================= launcher =======================
extern "C" void kernel_launch(void* const* d_in, const int* in_sizes, int n_in,
                              void* d_out, int out_size, void* d_ws, size_t ws_size,
                              hipStream_t stream) {
    const float* z      = (const float*)d_in[0];
    const float* emb    = (const float*)d_in[1];
    const float* ema_cs = (const float*)d_in[2];
    const float* ema_w  = (const float*)d_in[3];

    float* out = (float*)d_out;
    char*  wsb = (char*)d_ws;

    int*            cnt_i   = (int*)(wsb + WSB_CNTI);
    float*          lossbuf = (float*)(wsb + WSB_LOSS);
    float*          csum    = (float*)(wsb + WSB_CSUM);
    float*          dwacc   = (float*)(wsb + WSB_DWACC);
    float*          enorm   = (float*)(wsb + WSB_ENORM);
    int*            idx     = (int*)(wsb + WSB_IDX);
    unsigned short* e_hi    = (unsigned short*)(wsb + WSB_EHI);
    unsigned short* e_lo    = (unsigned short*)(wsb + WSB_ELO);
    int*            offsets = (int*)(wsb + WSB_OFFS);
    int*            cursor  = (int*)(wsb + WSB_CURS);
    int*            sorted  = (int*)(wsb + WSB_SORT);
    float*          best_d  = (float*)(wsb + WSB_BESTD);
    int*            best_i  = (int*)(wsb + WSB_BESTI);

    float* out_zq   = out + OUT_ZQ;
    float* out_loss = out + OUT_LOSS;
    float* out_idxf = out + OUT_IDX;
    float* out_emb  = out + OUT_EMB;
    float* out_cs   = out + OUT_CS;
    float* out_emaw = out + OUT_EMAW;

    hipMemsetAsync(d_ws, 0, WSB_MEMSET, stream);

    esplit_enorm_kernel<<<256, 256, 0, stream>>>(emb, e_hi, e_lo, enorm);
    argmin_kernel<<<1024, 256, 0, stream>>>(z, e_hi, e_lo, enorm, best_d, best_i);
    merge_kernel<<<128, 256, 0, stream>>>(best_d, best_i, idx, out_idxf, cnt_i);
    update_cs_kernel<<<1, 256, 0, stream>>>(ema_cs, cnt_i, out_cs, csum, offsets, cursor);
    scatter_kernel<<<128, 256, 0, stream>>>(idx, cursor, sorted);
    gather_kernel<<<8192, 256, 0, stream>>>(z, emb, idx, out_zq, lossbuf);
    dw_scatter_kernel<<<512, 256, 0, stream>>>(z, sorted, idx, dwacc);
    update_w_kernel<<<256, 256, 0, stream>>>(ema_w, dwacc, out_cs, csum, lossbuf,
                                             out_emb, out_emaw, out_loss);
}

// Round 5
// 263.794 us; speedup vs baseline: 1.7777x; 1.2045x over previous
//
#include <hip/hip_runtime.h>

#define DECAY_F 0.99f
#define OMD_F   0.01f
#define EPS_F   1e-5f

typedef __attribute__((ext_vector_type(8))) __bf16 bf16x8;
typedef __attribute__((ext_vector_type(4))) float  f32x4;

// ---------------- ws layout (byte offsets) ----------------
#define WSB_LOSS     0          // 256 f32 (1024 B)        [memset]
#define WSB_DWACC    1024       // 262144 f32 (1 MB)       [memset]
#define WSB_MEMSET   1049600    // memset range [0, this)
#define WSB_CSUM     1049600    // 1 f32
#define WSB_ENORM    1049664    // 1024 f32
#define WSB_IDX      1053760    // 32768 i32
#define WSB_EHI      1184832    // 262144 ushort
#define WSB_ELO      1709120    // 262144 ushort
#define WSB_SORT     2233408    // 32768 i32
#define WSB_BESTD    2364480    // 4*32768 f32
#define WSB_BESTI    2888768    // 4*32768 i32 (end 3413056)

// ---------------- out layout (float offsets) ----------------
#define OUT_ZQ    0
#define OUT_LOSS  8388608
#define OUT_IDX   8388609
#define OUT_EMB   8421377
#define OUT_CS    8683521
#define OUT_EMAW  8684545

// ---------- bf16 split helpers (RNE, no NaN inputs) ----------
__device__ __forceinline__ unsigned short f2bf(float x) {
    unsigned u = __builtin_bit_cast(unsigned, x);
    u += 0x7fffu + ((u >> 16) & 1u);
    return (unsigned short)(u >> 16);
}
__device__ __forceinline__ float bf2f(unsigned short h) {
    return __builtin_bit_cast(float, (unsigned)h << 16);
}
__device__ __forceinline__ void split8(const float4 a, const float4 b,
                                       uint4& hi, uint4& lo) {
    float f[8] = {a.x, a.y, a.z, a.w, b.x, b.y, b.z, b.w};
    unsigned short h[8], l[8];
    #pragma unroll
    for (int i = 0; i < 8; ++i) {
        h[i] = f2bf(f[i]);
        l[i] = f2bf(f[i] - bf2f(h[i]));
    }
    hi.x = (unsigned)h[0] | ((unsigned)h[1] << 16);
    hi.y = (unsigned)h[2] | ((unsigned)h[3] << 16);
    hi.z = (unsigned)h[4] | ((unsigned)h[5] << 16);
    hi.w = (unsigned)h[6] | ((unsigned)h[7] << 16);
    lo.x = (unsigned)l[0] | ((unsigned)l[1] << 16);
    lo.y = (unsigned)l[2] | ((unsigned)l[3] << 16);
    lo.z = (unsigned)l[4] | ((unsigned)l[5] << 16);
    lo.w = (unsigned)l[6] | ((unsigned)l[7] << 16);
}

// ---------- global -> LDS direct 16B copy ----------
__device__ __forceinline__ void load_lds16(const void* g, void* l) {
    __builtin_amdgcn_global_load_lds(
        (const __attribute__((address_space(1))) unsigned int*)g,
        (__attribute__((address_space(3))) unsigned int*)l, 16, 0, 0);
}

// ============ kernel 0: split embedding to bf16 hi/lo + ||e||^2 ============
__global__ __launch_bounds__(256)
void esplit_enorm_kernel(const float* __restrict__ emb,
                         unsigned short* __restrict__ e_hi,
                         unsigned short* __restrict__ e_lo,
                         float* __restrict__ enorm) {
    const int tid = threadIdx.x, lane = tid & 63, wv = tid >> 6;
    const int k = blockIdx.x * 4 + wv;
    const float4 v = *(const float4*)(emb + (size_t)k * 256 + lane * 4);
    float f[4] = {v.x, v.y, v.z, v.w};
    unsigned short h[4], l[4];
    #pragma unroll
    for (int i = 0; i < 4; ++i) { h[i] = f2bf(f[i]); l[i] = f2bf(f[i] - bf2f(h[i])); }
    uint2 hi, lo;
    hi.x = (unsigned)h[0] | ((unsigned)h[1] << 16);
    hi.y = (unsigned)h[2] | ((unsigned)h[3] << 16);
    lo.x = (unsigned)l[0] | ((unsigned)l[1] << 16);
    lo.y = (unsigned)l[2] | ((unsigned)l[3] << 16);
    *(uint2*)(e_hi + (size_t)k * 256 + lane * 4) = hi;
    *(uint2*)(e_lo + (size_t)k * 256 + lane * 4) = lo;
    float s = v.x * v.x + v.y * v.y + v.z * v.z + v.w * v.w;
    #pragma unroll
    for (int off = 32; off > 0; off >>= 1) s += __shfl_down(s, off);
    if (lane == 0) enorm[k] = s;
}

// ============ kernel 1: MFMA argmin, code-split blocks ============
// Grid 1024 = 256 row-groups x 4 code-splits. Block 128 rows x 256 codes,
// 4 waves (2x2), wave tile 64x128 = 4x8 of 16x16x32 MFMAs, kc=8 over D=256.
// 3-combo bf16 hi/lo split. XOR-swizzled stride-32 LDS. B staged via
// global_load_lds (swizzle folded into per-lane GLOBAL address; LDS side is
// lane-linear as HW requires). A split on the fly from 16 prefetch regs.
// Inner loop: A frags resident, B streamed per-j -> ~220 regs, no spills.
__global__ __launch_bounds__(256, 2)
void argmin_kernel(const float* __restrict__ z,
                   const unsigned short* __restrict__ e_hi,
                   const unsigned short* __restrict__ e_lo,
                   const float* __restrict__ enorm,
                   float* __restrict__ best_d, int* __restrict__ best_i) {
    __shared__ unsigned short Ah[128 * 32], Al[128 * 32];   // 8 KB each
    __shared__ unsigned short Bh[256 * 32], Bl[256 * 32];   // 16 KB each

    const int tid  = threadIdx.x;
    const int lane = tid & 63;
    const int wv   = tid >> 6;
    const int wy   = wv >> 1, wx = wv & 1;
    const int tx   = lane & 15, quad = lane >> 4;
    const int rowg = blockIdx.x & 255;
    const int csp  = blockIdx.x >> 8;
    const int row0 = rowg * 128;
    const int col0 = csp * 256;

    // ---- A staging map (2 segments of 8 floats per thread) ----
    const int rA0 = tid >> 2,         gA0 = tid & 3;
    const int rA1 = (tid + 256) >> 2, gA1 = (tid + 256) & 3;
    const float* zA0 = z + (size_t)(row0 + rA0) * 256 + gA0 * 8;
    const float* zA1 = z + (size_t)(row0 + rA1) * 256 + gA1 * 8;
    const int offA0 = rA0 * 32 + ((gA0 ^ (rA0 & 3)) << 3);
    const int offA1 = rA1 * 32 + ((gA1 ^ (rA1 & 3)) << 3);

    // ---- B staging map: 4 lds-direct instrs per array ----
    // instr i: LDS segs [i*256 + wv*64, +64), lane l -> seg s = base + l.
    // LDS is lane-linear; swizzle realized by permuting the GLOBAL granule.
    const unsigned short* gBh[4]; const unsigned short* gBl[4];
    unsigned short* lBh[4]; unsigned short* lBl[4];
    #pragma unroll
    for (int i = 0; i < 4; ++i) {
        const int s  = i * 256 + wv * 64 + lane;
        const int c  = s >> 2, gs = s & 3;
        const int g  = gs ^ (c & 3);
        gBh[i] = e_hi + (size_t)(col0 + c) * 256 + g * 8;
        gBl[i] = e_lo + (size_t)(col0 + c) * 256 + g * 8;
        lBh[i] = Bh + (size_t)(i * 256 + wv * 64) * 8;   // wave-uniform
        lBl[i] = Bl + (size_t)(i * 256 + wv * 64) * 8;
    }

    // ---- frag read offsets (halfs, swizzled) ----
    int offAf[4], offBf[8];
    #pragma unroll
    for (int i = 0; i < 4; ++i) {
        const int rt = wy * 64 + i * 16 + tx;
        offAf[i] = rt * 32 + ((quad ^ (rt & 3)) << 3);
    }
    #pragma unroll
    for (int j = 0; j < 8; ++j) {
        const int cb = wx * 128 + j * 16 + tx;
        offBf[j] = cb * 32 + ((quad ^ (cb & 3)) << 3);
    }

    f32x4 acc[4][8];
    #pragma unroll
    for (int i = 0; i < 4; ++i)
        #pragma unroll
        for (int j = 0; j < 8; ++j) acc[i][j] = (f32x4)0.0f;

    float4 pA[4];
    auto prefA = [&](int kc_) {
        const int o = kc_ * 32;
        pA[0] = *(const float4*)(zA0 + o);
        pA[1] = *(const float4*)(zA0 + o + 4);
        pA[2] = *(const float4*)(zA1 + o);
        pA[3] = *(const float4*)(zA1 + o + 4);
    };
    prefA(0);

    for (int kc = 0; kc < 8; ++kc) {
        __syncthreads();
        {   // A: split in regs -> LDS writes
            uint4 h0, l0, h1, l1;
            split8(pA[0], pA[1], h0, l0);
            split8(pA[2], pA[3], h1, l1);
            *(uint4*)(Ah + offA0) = h0; *(uint4*)(Al + offA0) = l0;
            *(uint4*)(Ah + offA1) = h1; *(uint4*)(Al + offA1) = l1;
        }
        // B: global -> LDS direct (drained by the next __syncthreads)
        #pragma unroll
        for (int i = 0; i < 4; ++i) {
            load_lds16(gBh[i] + kc * 32, lBh[i]);
            load_lds16(gBl[i] + kc * 32, lBl[i]);
        }
        __syncthreads();
        if (kc < 7) prefA(kc + 1);   // in flight behind the MFMAs

        bf16x8 ah[4], al[4];
        #pragma unroll
        for (int i = 0; i < 4; ++i) {
            ah[i] = __builtin_bit_cast(bf16x8, *(const uint4*)(Ah + offAf[i]));
            al[i] = __builtin_bit_cast(bf16x8, *(const uint4*)(Al + offAf[i]));
        }
        #pragma unroll
        for (int j = 0; j < 8; ++j) {
            const bf16x8 bh = __builtin_bit_cast(bf16x8, *(const uint4*)(Bh + offBf[j]));
            const bf16x8 bl = __builtin_bit_cast(bf16x8, *(const uint4*)(Bl + offBf[j]));
            #pragma unroll
            for (int i = 0; i < 4; ++i)
                acc[i][j] = __builtin_amdgcn_mfma_f32_16x16x32_bf16(ah[i], bh, acc[i][j], 0, 0, 0);
            #pragma unroll
            for (int i = 0; i < 4; ++i)
                acc[i][j] = __builtin_amdgcn_mfma_f32_16x16x32_bf16(al[i], bh, acc[i][j], 0, 0, 0);
            #pragma unroll
            for (int i = 0; i < 4; ++i)
                acc[i][j] = __builtin_amdgcn_mfma_f32_16x16x32_bf16(ah[i], bl, acc[i][j], 0, 0, 0);
        }
    }

    // ---- distances + in-thread argmin ----
    float bestd[4][4];
    int   besti[4][4];
    #pragma unroll
    for (int i = 0; i < 4; ++i)
        #pragma unroll
        for (int r = 0; r < 4; ++r) { bestd[i][r] = 3.4e38f; besti[i][r] = 0; }
    #pragma unroll
    for (int j = 0; j < 8; ++j) {
        const int col = col0 + wx * 128 + j * 16 + tx;
        const float en = enorm[col];
        #pragma unroll
        for (int i = 0; i < 4; ++i)
            #pragma unroll
            for (int r = 0; r < 4; ++r) {
                const float d = fmaf(-2.0f, acc[i][j][r], en);
                if (d < bestd[i][r] || (d == bestd[i][r] && col < besti[i][r])) {
                    bestd[i][r] = d; besti[i][r] = col;
                }
            }
    }

    // ---- butterfly over the 16 tx lanes ----
    #pragma unroll
    for (int m = 1; m < 16; m <<= 1) {
        #pragma unroll
        for (int i = 0; i < 4; ++i)
            #pragma unroll
            for (int r = 0; r < 4; ++r) {
                const float od = __shfl_xor(bestd[i][r], m);
                const int   oi = __shfl_xor(besti[i][r], m);
                if (od < bestd[i][r] || (od == bestd[i][r] && oi < besti[i][r])) {
                    bestd[i][r] = od; besti[i][r] = oi;
                }
            }
    }

    // ---- merge wx halves via LDS, write per-split best ----
    __syncthreads();
    float* mg_d = (float*)Ah;                 // [2][128]
    int*   mg_i = (int*)Ah + 256;
    if (tx == 0) {
        #pragma unroll
        for (int i = 0; i < 4; ++i)
            #pragma unroll
            for (int r = 0; r < 4; ++r) {
                const int rb = wy * 64 + i * 16 + quad * 4 + r;
                mg_d[wx * 128 + rb] = bestd[i][r];
                mg_i[wx * 128 + rb] = besti[i][r];
            }
    }
    __syncthreads();
    if (tid < 128) {
        float d0 = mg_d[tid];             int i0 = mg_i[tid];
        const float d1 = mg_d[128 + tid]; const int i1 = mg_i[128 + tid];
        if (d1 < d0 || (d1 == d0 && i1 < i0)) { d0 = d1; i0 = i1; }
        best_d[csp * 32768 + row0 + tid] = d0;
        best_i[csp * 32768 + row0 + tid] = i0;
    }
}

// ============ kernel 2: single-block merge + counts + cs/csum + scan + scatter ===
__global__ __launch_bounds__(1024)
void sortmerge_kernel(const float* __restrict__ best_d, const int* __restrict__ best_i,
                      const float* __restrict__ ema_cs,
                      int* __restrict__ idx, float* __restrict__ idxf,
                      int* __restrict__ sorted,
                      float* __restrict__ out_cs, float* __restrict__ csum) {
    __shared__ int   cnt[1024];
    __shared__ int   cur[1024];
    __shared__ int   wtmp[16];
    __shared__ float wred[16];
    const int t = threadIdx.x, lane = t & 63, wv = t >> 6;
    cnt[t] = 0;
    __syncthreads();

    int ki[32];
    #pragma unroll
    for (int s = 0; s < 32; ++s) {
        const int r = s * 1024 + t;
        float d = best_d[r]; int i0 = best_i[r];
        #pragma unroll
        for (int sp = 1; sp < 4; ++sp) {
            const float ds  = best_d[sp * 32768 + r];
            const int   is_ = best_i[sp * 32768 + r];
            if (ds < d) { d = ds; i0 = is_; }   // splits ascend in code: strict <
        }
        ki[s] = i0;
        idx[r]  = i0;
        idxf[r] = (float)i0;
        atomicAdd(&cnt[i0], 1);
    }
    __syncthreads();

    const int   c = cnt[t];
    const float f = DECAY_F * ema_cs[t] + OMD_F * (float)c;
    out_cs[t] = f;
    float fs = f;
    #pragma unroll
    for (int o = 32; o > 0; o >>= 1) fs += __shfl_down(fs, o);
    if (lane == 0) wred[wv] = fs;
    int v = c;
    #pragma unroll
    for (int o = 1; o < 64; o <<= 1) { const int u = __shfl_up(v, o); if (lane >= o) v += u; }
    if (lane == 63) wtmp[wv] = v;
    __syncthreads();
    if (t == 0) { float s2 = 0.f; for (int w = 0; w < 16; ++w) s2 += wred[w]; csum[0] = s2; }
    int wbase = 0;
    #pragma unroll
    for (int w = 0; w < 16; ++w) if (w < wv) wbase += wtmp[w];
    cur[t] = wbase + v - c;   // exclusive prefix
    __syncthreads();

    #pragma unroll
    for (int s = 0; s < 32; ++s) {
        const int r = s * 1024 + t;
        const int p = atomicAdd(&cur[ki[s]], 1);
        sorted[p] = r;
    }
}

// ============ kernel 3 (fat): gather z_q + loss  |  dw run-length scatter ============
__global__ __launch_bounds__(256)
void fat_kernel(const float* __restrict__ z, const float* __restrict__ emb,
                const int* __restrict__ idx, const int* __restrict__ sorted,
                float* __restrict__ out_zq, float* __restrict__ lossbuf,
                float* __restrict__ dwacc) {
    const int b    = blockIdx.x;
    const int lane = threadIdx.x & 63;
    const int wvv  = threadIdx.x >> 6;

    if (b < 8192) {
        // ---- gather part ----
        const int n = b * 4 + wvv;
        const int k = idx[n];
        const float4 e4 = *(const float4*)(emb + (size_t)k * 256 + lane * 4);
        const float4 x4 = *(const float4*)(z   + (size_t)n * 256 + lane * 4);
        *(float4*)(out_zq + (size_t)n * 256 + lane * 4) = e4;
        const float dx = e4.x - x4.x, dy = e4.y - x4.y, dz = e4.z - x4.z, dww = e4.w - x4.w;
        float s = dx * dx + dy * dy + dz * dz + dww * dww;
        #pragma unroll
        for (int off = 32; off > 0; off >>= 1) s += __shfl_down(s, off);
        if (lane == 0) atomicAdd(&lossbuf[n & 255], s);
    } else {
        // ---- dw part: wave owns 16 sorted rows, run-length flush ----
        const int w  = (b - 8192) * 4 + wvv;
        const int r0 = w * 16;
        float4 s = make_float4(0.f, 0.f, 0.f, 0.f);
        int krun = idx[sorted[r0]];
        for (int j = 0; j < 16; ++j) {
            const int row = sorted[r0 + j];
            const int k   = idx[row];
            if (k != krun) {
                float* p = dwacc + (size_t)krun * 256 + lane * 4;
                atomicAdd(p + 0, s.x); atomicAdd(p + 1, s.y);
                atomicAdd(p + 2, s.z); atomicAdd(p + 3, s.w);
                s = make_float4(0.f, 0.f, 0.f, 0.f);
                krun = k;
            }
            const float4 vv = *(const float4*)(z + (size_t)row * 256 + lane * 4);
            s.x += vv.x; s.y += vv.y; s.z += vv.z; s.w += vv.w;
        }
        float* p = dwacc + (size_t)krun * 256 + lane * 4;
        atomicAdd(p + 0, s.x); atomicAdd(p + 1, s.y);
        atomicAdd(p + 2, s.z); atomicAdd(p + 3, s.w);
    }
}

// ============ kernel 4: EMA-w / embedding epilogue + loss finalize ============
__global__ __launch_bounds__(256)
void update_w_kernel(const float* __restrict__ ema_w, const float* __restrict__ dwacc,
                     const float* __restrict__ out_cs, const float* __restrict__ csum,
                     const float* __restrict__ lossbuf,
                     float* __restrict__ out_emb, float* __restrict__ out_emaw,
                     float* __restrict__ out_loss) {
    __shared__ float red[256];
    const int t = threadIdx.x;
    if (blockIdx.x == 0) {
        red[t] = lossbuf[t]; __syncthreads();
        #pragma unroll
        for (int off = 128; off > 0; off >>= 1) {
            if (t < off) red[t] += red[t + off];
            __syncthreads();
        }
        if (t == 0) out_loss[0] = 1.25f * red[0] / 8388608.0f;
    }

    const int g = blockIdx.x * 256 + t;          // float4 slot, 0..65535
    const int k = g >> 6;
    const float n_total = csum[0];
    const float cs = (out_cs[k] + EPS_F) / (n_total + 1024.0f * EPS_F) * n_total;

    const float4 w4 = *(const float4*)(ema_w + (size_t)g * 4);
    const float4 d4 = *(const float4*)(dwacc + (size_t)g * 4);
    float4 nw, ne;
    nw.x = DECAY_F * w4.x + OMD_F * d4.x;
    nw.y = DECAY_F * w4.y + OMD_F * d4.y;
    nw.z = DECAY_F * w4.z + OMD_F * d4.z;
    nw.w = DECAY_F * w4.w + OMD_F * d4.w;
    ne.x = nw.x / cs; ne.y = nw.y / cs; ne.z = nw.z / cs; ne.w = nw.w / cs;
    *(float4*)(out_emaw + (size_t)g * 4) = nw;
    *(float4*)(out_emb  + (size_t)g * 4) = ne;
}

// ======================= launcher =======================
extern "C" void kernel_launch(void* const* d_in, const int* in_sizes, int n_in,
                              void* d_out, int out_size, void* d_ws, size_t ws_size,
                              hipStream_t stream) {
    const float* z      = (const float*)d_in[0];
    const float* emb    = (const float*)d_in[1];
    const float* ema_cs = (const float*)d_in[2];
    const float* ema_w  = (const float*)d_in[3];

    float* out = (float*)d_out;
    char*  wsb = (char*)d_ws;

    float*          lossbuf = (float*)(wsb + WSB_LOSS);
    float*          dwacc   = (float*)(wsb + WSB_DWACC);
    float*          csum    = (float*)(wsb + WSB_CSUM);
    float*          enorm   = (float*)(wsb + WSB_ENORM);
    int*            idx     = (int*)(wsb + WSB_IDX);
    unsigned short* e_hi    = (unsigned short*)(wsb + WSB_EHI);
    unsigned short* e_lo    = (unsigned short*)(wsb + WSB_ELO);
    int*            sorted  = (int*)(wsb + WSB_SORT);
    float*          best_d  = (float*)(wsb + WSB_BESTD);
    int*            best_i  = (int*)(wsb + WSB_BESTI);

    float* out_zq   = out + OUT_ZQ;
    float* out_loss = out + OUT_LOSS;
    float* out_idxf = out + OUT_IDX;
    float* out_emb  = out + OUT_EMB;
    float* out_cs   = out + OUT_CS;
    float* out_emaw = out + OUT_EMAW;

    hipMemsetAsync(d_ws, 0, WSB_MEMSET, stream);

    esplit_enorm_kernel<<<256, 256, 0, stream>>>(emb, e_hi, e_lo, enorm);
    argmin_kernel<<<1024, 256, 0, stream>>>(z, e_hi, e_lo, enorm, best_d, best_i);
    sortmerge_kernel<<<1, 1024, 0, stream>>>(best_d, best_i, ema_cs, idx, out_idxf,
                                             sorted, out_cs, csum);
    fat_kernel<<<8704, 256, 0, stream>>>(z, emb, idx, sorted, out_zq, lossbuf, dwacc);
    update_w_kernel<<<256, 256, 0, stream>>>(ema_w, dwacc, out_cs, csum, lossbuf,
                                             out_emb, out_emaw, out_loss);
}

// Round 6
// 251.387 us; speedup vs baseline: 1.8655x; 1.0494x over previous
//
#include <hip/hip_runtime.h>

#define DECAY_F 0.99f
#define OMD_F   0.01f
#define EPS_F   1e-5f

typedef __attribute__((ext_vector_type(8)))  __bf16 bf16x8;
typedef __attribute__((ext_vector_type(16))) float  f32x16;

// ---------------- ws layout (byte offsets) ----------------
#define WSB_CNTI     0          // 1024 i32 (4096)          [memset]
#define WSB_LOSS     4096       // 256 f32 (1024)           [memset]
#define WSB_DWACC    8192       // 262144 f32 (1 MB)        [memset]
#define WSB_MEMSET   1056768    // memset range [0, this)
#define WSB_CSUM     1056768    // 1 f32
#define WSB_ENORM    1056832    // 1024 f32
#define WSB_IDX      1060928    // 32768 i32
#define WSB_EHI      1192000    // 262144 ushort
#define WSB_ELO      1716288    // 262144 ushort
#define WSB_SORT     2240576    // 32768 i32
#define WSB_CURS     2371648    // 1024 i32
#define WSB_BESTD    2375744    // 4*32768 f32
#define WSB_BESTI    2900032    // 4*32768 i32 (end 3424320)

// ---------------- out layout (float offsets) ----------------
#define OUT_ZQ    0
#define OUT_LOSS  8388608
#define OUT_IDX   8388609
#define OUT_EMB   8421377
#define OUT_CS    8683521
#define OUT_EMAW  8684545

// ---------- bf16 split helpers (RNE, no NaN inputs) ----------
__device__ __forceinline__ unsigned short f2bf(float x) {
    unsigned u = __builtin_bit_cast(unsigned, x);
    u += 0x7fffu + ((u >> 16) & 1u);
    return (unsigned short)(u >> 16);
}
__device__ __forceinline__ float bf2f(unsigned short h) {
    return __builtin_bit_cast(float, (unsigned)h << 16);
}
__device__ __forceinline__ void split8(const float4 a, const float4 b,
                                       uint4& hi, uint4& lo) {
    float f[8] = {a.x, a.y, a.z, a.w, b.x, b.y, b.z, b.w};
    unsigned short h[8], l[8];
    #pragma unroll
    for (int i = 0; i < 8; ++i) {
        h[i] = f2bf(f[i]);
        l[i] = f2bf(f[i] - bf2f(h[i]));
    }
    hi.x = (unsigned)h[0] | ((unsigned)h[1] << 16);
    hi.y = (unsigned)h[2] | ((unsigned)h[3] << 16);
    hi.z = (unsigned)h[4] | ((unsigned)h[5] << 16);
    hi.w = (unsigned)h[6] | ((unsigned)h[7] << 16);
    lo.x = (unsigned)l[0] | ((unsigned)l[1] << 16);
    lo.y = (unsigned)l[2] | ((unsigned)l[3] << 16);
    lo.z = (unsigned)l[4] | ((unsigned)l[5] << 16);
    lo.w = (unsigned)l[6] | ((unsigned)l[7] << 16);
}

// ---------- global -> LDS direct 16B copy ----------
__device__ __forceinline__ void load_lds16(const void* g, void* l) {
    __builtin_amdgcn_global_load_lds(
        (const __attribute__((address_space(1))) unsigned int*)g,
        (__attribute__((address_space(3))) unsigned int*)l, 16, 0, 0);
}

// ============ kernel 0: split embedding to bf16 hi/lo + ||e||^2 ============
__global__ __launch_bounds__(256)
void esplit_enorm_kernel(const float* __restrict__ emb,
                         unsigned short* __restrict__ e_hi,
                         unsigned short* __restrict__ e_lo,
                         float* __restrict__ enorm) {
    const int tid = threadIdx.x, lane = tid & 63, wv = tid >> 6;
    const int k = blockIdx.x * 4 + wv;
    const float4 v = *(const float4*)(emb + (size_t)k * 256 + lane * 4);
    float f[4] = {v.x, v.y, v.z, v.w};
    unsigned short h[4], l[4];
    #pragma unroll
    for (int i = 0; i < 4; ++i) { h[i] = f2bf(f[i]); l[i] = f2bf(f[i] - bf2f(h[i])); }
    uint2 hi, lo;
    hi.x = (unsigned)h[0] | ((unsigned)h[1] << 16);
    hi.y = (unsigned)h[2] | ((unsigned)h[3] << 16);
    lo.x = (unsigned)l[0] | ((unsigned)l[1] << 16);
    lo.y = (unsigned)l[2] | ((unsigned)l[3] << 16);
    *(uint2*)(e_hi + (size_t)k * 256 + lane * 4) = hi;
    *(uint2*)(e_lo + (size_t)k * 256 + lane * 4) = lo;
    float s = v.x * v.x + v.y * v.y + v.z * v.z + v.w * v.w;
    #pragma unroll
    for (int off = 32; off > 0; off >>= 1) s += __shfl_down(s, off);
    if (lane == 0) enorm[k] = s;
}

// ============ kernel 1: MFMA argmin (32x32x16, code-split blocks) ============
// Grid 1024 = 256 row-groups x 4 code-splits. Block 128 rows x 256 codes,
// 4 waves (2x2), wave tile 64x128 = 2x4 grid of 32x32 tiles, BK=32 (2 kk
// sub-chunks of K=16). 3-combo bf16 hi/lo split. Granule swizzle
// g_phys = g ^ ((row>>1)&3): all 8 lanes of each b128 phase hit distinct
// bank quads -> conflict-free. B staged via global_load_lds (lane-linear
// LDS; swizzle folded into the GLOBAL granule address).
__global__ __launch_bounds__(256, 2)
void argmin_kernel(const float* __restrict__ z,
                   const unsigned short* __restrict__ e_hi,
                   const unsigned short* __restrict__ e_lo,
                   const float* __restrict__ enorm,
                   float* __restrict__ best_d, int* __restrict__ best_i) {
    __shared__ unsigned short Ah[128 * 32], Al[128 * 32];   // 8 KB each
    __shared__ unsigned short Bh[256 * 32], Bl[256 * 32];   // 16 KB each

    const int tid  = threadIdx.x;
    const int lane = tid & 63;
    const int wv   = tid >> 6;
    const int wy   = wv >> 1, wx = wv & 1;
    const int l31  = lane & 31, lh = lane >> 5;
    const int rowg = blockIdx.x & 255;
    const int csp  = blockIdx.x >> 8;
    const int row0 = rowg * 128;
    const int col0 = csp * 256;

    // ---- A staging map (2 granules of 8 floats per thread) ----
    const int rA0 = tid >> 2,  gA = tid & 3;
    const int rA1 = rA0 + 64;
    const float* zA0 = z + (size_t)(row0 + rA0) * 256 + gA * 8;
    const float* zA1 = z + (size_t)(row0 + rA1) * 256 + gA * 8;
    const int offA0 = rA0 * 32 + ((gA ^ ((rA0 >> 1) & 3)) << 3);
    const int offA1 = rA1 * 32 + ((gA ^ ((rA1 >> 1) & 3)) << 3);

    // ---- B staging: 4 lds-direct instrs per array; lane-linear LDS ----
    size_t gBoff[4];
    unsigned short* lB[4];
    #pragma unroll
    for (int i = 0; i < 4; ++i) {
        const int s = i * 256 + wv * 64 + lane;
        const int c = s >> 2, gp = s & 3;
        const int gl = gp ^ ((c >> 1) & 3);
        gBoff[i] = (size_t)(col0 + c) * 256 + gl * 8;
        lB[i]    = (unsigned short*)0 + (size_t)(i * 256 + wv * 64) * 8; // offset only
    }

    // ---- frag read offsets (halfs, swizzled): g_log = kk*2 + lh ----
    int offAf[2][2], offBf[4][2];
    #pragma unroll
    for (int i = 0; i < 2; ++i) {
        const int rt = wy * 64 + i * 32 + l31;
        #pragma unroll
        for (int kk = 0; kk < 2; ++kk)
            offAf[i][kk] = rt * 32 + (((kk * 2 + lh) ^ ((rt >> 1) & 3)) << 3);
    }
    #pragma unroll
    for (int j = 0; j < 4; ++j) {
        const int cb = wx * 128 + j * 32 + l31;
        #pragma unroll
        for (int kk = 0; kk < 2; ++kk)
            offBf[j][kk] = cb * 32 + (((kk * 2 + lh) ^ ((cb >> 1) & 3)) << 3);
    }

    f32x16 acc[2][4];
    #pragma unroll
    for (int i = 0; i < 2; ++i)
        #pragma unroll
        for (int j = 0; j < 4; ++j) acc[i][j] = (f32x16)0.0f;

    float4 pA[4];
    auto prefA = [&](int kc_) {
        const int o = kc_ * 32;
        pA[0] = *(const float4*)(zA0 + o);
        pA[1] = *(const float4*)(zA0 + o + 4);
        pA[2] = *(const float4*)(zA1 + o);
        pA[3] = *(const float4*)(zA1 + o + 4);
    };
    prefA(0);

    for (int kc = 0; kc < 8; ++kc) {
        __syncthreads();
        {   // A: split in regs -> LDS writes
            uint4 h0, l0, h1, l1;
            split8(pA[0], pA[1], h0, l0);
            split8(pA[2], pA[3], h1, l1);
            *(uint4*)(Ah + offA0) = h0; *(uint4*)(Al + offA0) = l0;
            *(uint4*)(Ah + offA1) = h1; *(uint4*)(Al + offA1) = l1;
        }
        // B: global -> LDS direct (drained by the next __syncthreads)
        #pragma unroll
        for (int i = 0; i < 4; ++i) {
            load_lds16(e_hi + gBoff[i] + kc * 32, Bh + (size_t)(lB[i] - (unsigned short*)0));
            load_lds16(e_lo + gBoff[i] + kc * 32, Bl + (size_t)(lB[i] - (unsigned short*)0));
        }
        __syncthreads();
        if (kc < 7) prefA(kc + 1);

        #pragma unroll
        for (int kk = 0; kk < 2; ++kk) {
            bf16x8 ah[2], al[2], bh[4], bl[4];
            #pragma unroll
            for (int i = 0; i < 2; ++i) {
                ah[i] = __builtin_bit_cast(bf16x8, *(const uint4*)(Ah + offAf[i][kk]));
                al[i] = __builtin_bit_cast(bf16x8, *(const uint4*)(Al + offAf[i][kk]));
            }
            #pragma unroll
            for (int j = 0; j < 4; ++j) {
                bh[j] = __builtin_bit_cast(bf16x8, *(const uint4*)(Bh + offBf[j][kk]));
                bl[j] = __builtin_bit_cast(bf16x8, *(const uint4*)(Bl + offBf[j][kk]));
            }
            #pragma unroll
            for (int j = 0; j < 4; ++j)
                #pragma unroll
                for (int i = 0; i < 2; ++i)
                    acc[i][j] = __builtin_amdgcn_mfma_f32_32x32x16_bf16(ah[i], bh[j], acc[i][j], 0, 0, 0);
            #pragma unroll
            for (int j = 0; j < 4; ++j)
                #pragma unroll
                for (int i = 0; i < 2; ++i)
                    acc[i][j] = __builtin_amdgcn_mfma_f32_32x32x16_bf16(al[i], bh[j], acc[i][j], 0, 0, 0);
            #pragma unroll
            for (int j = 0; j < 4; ++j)
                #pragma unroll
                for (int i = 0; i < 2; ++i)
                    acc[i][j] = __builtin_amdgcn_mfma_f32_32x32x16_bf16(ah[i], bl[j], acc[i][j], 0, 0, 0);
        }
    }

    // ---- distances + running argmin over j-tiles (codes ascending) ----
    // C layout: col = lane&31, row = (reg&3) + 8*(reg>>2) + 4*(lane>>5)
    float bestd[2][16];
    int   besti[2][16];
    #pragma unroll
    for (int i = 0; i < 2; ++i)
        #pragma unroll
        for (int r = 0; r < 16; ++r) { bestd[i][r] = 3.4e38f; besti[i][r] = 0; }
    #pragma unroll
    for (int j = 0; j < 4; ++j) {
        const int col = col0 + wx * 128 + j * 32 + l31;
        const float en = enorm[col];
        #pragma unroll
        for (int i = 0; i < 2; ++i)
            #pragma unroll
            for (int r = 0; r < 16; ++r) {
                const float d = fmaf(-2.0f, acc[i][j][r], en);
                if (d < bestd[i][r] || (d == bestd[i][r] && col < besti[i][r])) {
                    bestd[i][r] = d; besti[i][r] = col;
                }
            }
    }

    // ---- butterfly over the 32 col lanes (keeps lane>>5 fixed) ----
    #pragma unroll
    for (int m = 1; m < 32; m <<= 1) {
        #pragma unroll
        for (int i = 0; i < 2; ++i)
            #pragma unroll
            for (int r = 0; r < 16; ++r) {
                const float od = __shfl_xor(bestd[i][r], m);
                const int   oi = __shfl_xor(besti[i][r], m);
                if (od < bestd[i][r] || (od == bestd[i][r] && oi < besti[i][r])) {
                    bestd[i][r] = od; besti[i][r] = oi;
                }
            }
    }

    // ---- merge wx halves via LDS, write per-split best ----
    __syncthreads();
    float* mg_d = (float*)Ah;                 // [2][128]
    int*   mg_i = (int*)Ah + 256;
    if (l31 == 0) {
        #pragma unroll
        for (int i = 0; i < 2; ++i)
            #pragma unroll
            for (int r = 0; r < 16; ++r) {
                const int rloc = wy * 64 + i * 32 + (r & 3) + 8 * (r >> 2) + 4 * lh;
                mg_d[wx * 128 + rloc] = bestd[i][r];
                mg_i[wx * 128 + rloc] = besti[i][r];
            }
    }
    __syncthreads();
    if (tid < 128) {
        float d0 = mg_d[tid];             int i0 = mg_i[tid];
        const float d1 = mg_d[128 + tid]; const int i1 = mg_i[128 + tid];
        if (d1 < d0 || (d1 == d0 && i1 < i0)) { d0 = d1; i0 = i1; }
        best_d[csp * 32768 + row0 + tid] = d0;
        best_i[csp * 32768 + row0 + tid] = i0;
    }
}

// ============ kernel 2: merge splits + gather z_q + counts ============
__global__ __launch_bounds__(256)
void mergegather_kernel(const float* __restrict__ emb,
                        const float* __restrict__ best_d, const int* __restrict__ best_i,
                        int* __restrict__ idx, float* __restrict__ idxf,
                        float* __restrict__ out_zq, int* __restrict__ cnt) {
    const int tid = threadIdx.x, lane = tid & 63;
    const int n = blockIdx.x * 4 + (tid >> 6);
    float d = best_d[n]; int i0 = best_i[n];
    #pragma unroll
    for (int s = 1; s < 4; ++s) {
        const float ds = best_d[s * 32768 + n];
        const int   ii = best_i[s * 32768 + n];
        if (ds < d) { d = ds; i0 = ii; }   // splits ascend in code: strict <
    }
    if (lane == 0) { idx[n] = i0; idxf[n] = (float)i0; atomicAdd(&cnt[i0], 1); }
    const float4 e4 = *(const float4*)(emb + (size_t)i0 * 256 + lane * 4);
    *(float4*)(out_zq + (size_t)n * 256 + lane * 4) = e4;
}

// ============ kernel 3: scan — out_cs, csum, exclusive cursor ============
__global__ __launch_bounds__(1024)
void scan_kernel(const float* __restrict__ ema_cs, const int* __restrict__ cnt,
                 float* __restrict__ out_cs, float* __restrict__ csum,
                 int* __restrict__ cursor) {
    __shared__ int   wtmp[16];
    __shared__ float wred[16];
    const int t = threadIdx.x, lane = t & 63, wv = t >> 6;
    const int c = cnt[t];
    const float f = DECAY_F * ema_cs[t] + OMD_F * (float)c;
    out_cs[t] = f;
    float fs = f;
    #pragma unroll
    for (int o = 32; o > 0; o >>= 1) fs += __shfl_down(fs, o);
    if (lane == 0) wred[wv] = fs;
    int v = c;
    #pragma unroll
    for (int o = 1; o < 64; o <<= 1) { const int u = __shfl_up(v, o); if (lane >= o) v += u; }
    if (lane == 63) wtmp[wv] = v;
    __syncthreads();
    if (t == 0) { float s2 = 0.f; for (int w = 0; w < 16; ++w) s2 += wred[w]; csum[0] = s2; }
    int wbase = 0;
    #pragma unroll
    for (int w = 0; w < 16; ++w) if (w < wv) wbase += wtmp[w];
    cursor[t] = wbase + v - c;
}

// ============ kernel 4: scatter rows into code-sorted order ============
__global__ __launch_bounds__(256)
void scatter_kernel(const int* __restrict__ idx, int* __restrict__ cursor,
                    int* __restrict__ sorted) {
    const int n = blockIdx.x * 256 + threadIdx.x;
    const int k = idx[n];
    const int p = atomicAdd(&cursor[k], 1);
    sorted[p] = n;
}

// ============ kernel 5: dw + loss — wave per 64 sorted rows, run-length ============
// loss per run computed algebraically: sum||z-e||^2 = sum(z^2) - 2 e.S + cnt*||e||^2
__global__ __launch_bounds__(256)
void dw_kernel(const float* __restrict__ z, const float* __restrict__ emb,
               const float* __restrict__ enorm,
               const int* __restrict__ sorted, const int* __restrict__ idx,
               float* __restrict__ dwacc, float* __restrict__ lossbuf) {
    const int lane = threadIdx.x & 63;
    const int w    = blockIdx.x * 4 + (threadIdx.x >> 6);
    const int r0   = w * 64;
    const int srow = sorted[r0 + lane];
    const int skey = idx[srow];

    float4 s = make_float4(0.f, 0.f, 0.f, 0.f);
    float sumsq = 0.f;
    int cntr = 0;
    int krun = __shfl(skey, 0);

    auto flush = [&](int k) {
        const float4 e = *(const float4*)(emb + (size_t)k * 256 + lane * 4);
        float val = sumsq - 2.0f * (e.x * s.x + e.y * s.y + e.z * s.z + e.w * s.w);
        #pragma unroll
        for (int off = 32; off > 0; off >>= 1) val += __shfl_down(val, off);
        if (lane == 0) atomicAdd(&lossbuf[k & 255], val + (float)cntr * enorm[k]);
        float* p = dwacc + (size_t)k * 256 + lane * 4;
        atomicAdd(p + 0, s.x); atomicAdd(p + 1, s.y);
        atomicAdd(p + 2, s.z); atomicAdd(p + 3, s.w);
    };

    #pragma unroll 8
    for (int j = 0; j < 64; ++j) {
        const int row = __shfl(srow, j);
        const int k   = __shfl(skey, j);
        if (k != krun) {
            flush(krun);
            s = make_float4(0.f, 0.f, 0.f, 0.f);
            sumsq = 0.f; cntr = 0; krun = k;
        }
        const float4 v = *(const float4*)(z + (size_t)row * 256 + lane * 4);
        s.x += v.x; s.y += v.y; s.z += v.z; s.w += v.w;
        sumsq += v.x * v.x + v.y * v.y + v.z * v.z + v.w * v.w;
        ++cntr;
    }
    flush(krun);
}

// ============ kernel 6: EMA-w / embedding epilogue + loss finalize ============
__global__ __launch_bounds__(256)
void update_w_kernel(const float* __restrict__ ema_w, const float* __restrict__ dwacc,
                     const float* __restrict__ out_cs, const float* __restrict__ csum,
                     const float* __restrict__ lossbuf,
                     float* __restrict__ out_emb, float* __restrict__ out_emaw,
                     float* __restrict__ out_loss) {
    __shared__ float red[256];
    const int t = threadIdx.x;
    if (blockIdx.x == 0) {
        red[t] = lossbuf[t]; __syncthreads();
        #pragma unroll
        for (int off = 128; off > 0; off >>= 1) {
            if (t < off) red[t] += red[t + off];
            __syncthreads();
        }
        if (t == 0) out_loss[0] = 1.25f * red[0] / 8388608.0f;
    }

    const int g = blockIdx.x * 256 + t;          // float4 slot, 0..65535
    const int k = g >> 6;
    const float n_total = csum[0];
    const float cs = (out_cs[k] + EPS_F) / (n_total + 1024.0f * EPS_F) * n_total;

    const float4 w4 = *(const float4*)(ema_w + (size_t)g * 4);
    const float4 d4 = *(const float4*)(dwacc + (size_t)g * 4);
    float4 nw, ne;
    nw.x = DECAY_F * w4.x + OMD_F * d4.x;
    nw.y = DECAY_F * w4.y + OMD_F * d4.y;
    nw.z = DECAY_F * w4.z + OMD_F * d4.z;
    nw.w = DECAY_F * w4.w + OMD_F * d4.w;
    ne.x = nw.x / cs; ne.y = nw.y / cs; ne.z = nw.z / cs; ne.w = nw.w / cs;
    *(float4*)(out_emaw + (size_t)g * 4) = nw;
    *(float4*)(out_emb  + (size_t)g * 4) = ne;
}

// ======================= launcher =======================
extern "C" void kernel_launch(void* const* d_in, const int* in_sizes, int n_in,
                              void* d_out, int out_size, void* d_ws, size_t ws_size,
                              hipStream_t stream) {
    const float* z      = (const float*)d_in[0];
    const float* emb    = (const float*)d_in[1];
    const float* ema_cs = (const float*)d_in[2];
    const float* ema_w  = (const float*)d_in[3];

    float* out = (float*)d_out;
    char*  wsb = (char*)d_ws;

    int*            cnt     = (int*)(wsb + WSB_CNTI);
    float*          lossbuf = (float*)(wsb + WSB_LOSS);
    float*          dwacc   = (float*)(wsb + WSB_DWACC);
    float*          csum    = (float*)(wsb + WSB_CSUM);
    float*          enorm   = (float*)(wsb + WSB_ENORM);
    int*            idx     = (int*)(wsb + WSB_IDX);
    unsigned short* e_hi    = (unsigned short*)(wsb + WSB_EHI);
    unsigned short* e_lo    = (unsigned short*)(wsb + WSB_ELO);
    int*            sorted  = (int*)(wsb + WSB_SORT);
    int*            cursor  = (int*)(wsb + WSB_CURS);
    float*          best_d  = (float*)(wsb + WSB_BESTD);
    int*            best_i  = (int*)(wsb + WSB_BESTI);

    float* out_zq   = out + OUT_ZQ;
    float* out_loss = out + OUT_LOSS;
    float* out_idxf = out + OUT_IDX;
    float* out_emb  = out + OUT_EMB;
    float* out_cs   = out + OUT_CS;
    float* out_emaw = out + OUT_EMAW;

    hipMemsetAsync(d_ws, 0, WSB_MEMSET, stream);

    esplit_enorm_kernel<<<256, 256, 0, stream>>>(emb, e_hi, e_lo, enorm);
    argmin_kernel<<<1024, 256, 0, stream>>>(z, e_hi, e_lo, enorm, best_d, best_i);
    mergegather_kernel<<<8192, 256, 0, stream>>>(emb, best_d, best_i, idx, out_idxf,
                                                 out_zq, cnt);
    scan_kernel<<<1, 1024, 0, stream>>>(ema_cs, cnt, out_cs, csum, cursor);
    scatter_kernel<<<128, 256, 0, stream>>>(idx, cursor, sorted);
    dw_kernel<<<128, 256, 0, stream>>>(z, emb, enorm, sorted, idx, dwacc, lossbuf);
    update_w_kernel<<<256, 256, 0, stream>>>(ema_w, dwacc, out_cs, csum, lossbuf,
                                             out_emb, out_emaw, out_loss);
}